// Round 4
// baseline (290.162 us; speedup 1.0000x reference)
//
#include <hip/hip_runtime.h>

// QRNN fused: causal conv1d(window=2) as f16 MFMA GEMM + gates + fo-pool scan.
// Shapes: B=8, T=2048, C=1024, U=1024 -> GEMM M=16384, K=2048, N=3072.
// R4: same 8-phase/counted-vmcnt skeleton as R3; MFMA shape 16x16x32 -> 32x32x16
//     (higher measured pipe ceiling, half the instruction count).

typedef _Float16 f16;
typedef _Float16 f16x8 __attribute__((ext_vector_type(8)));
typedef float    f32x16 __attribute__((ext_vector_type(16)));

#define Bq 8
#define Tq 2048
#define Cq 1024
#define Uq 1024
#define Mq (Bq*Tq)    // 16384
#define Kq (2*Cq)     // 2048
#define Nq (3*Uq)     // 3072
#define NCH 32
#define CHL (Tq/NCH)

#define AS1 __attribute__((address_space(1)))
#define AS3 __attribute__((address_space(3)))

// ---------------- prep: Xs[b][1+t][c] = x[b][t][c] (f16), Xs[b][0][:] = 0 ----------------
__global__ void prep_xs(const float* __restrict__ x, f16* __restrict__ Xs) {
    long long idx = ((long long)blockIdx.x * blockDim.x + threadIdx.x) * 8;
    int c = (int)(idx & (Cq - 1));
    long long row = idx >> 10;
    int tp = (int)(row % (Tq + 1));
    int b  = (int)(row / (Tq + 1));
    f16x8 o;
    if (tp == 0) {
#pragma unroll
        for (int j = 0; j < 8; j++) o[j] = (f16)0.0f;
    } else {
        const float* src = x + (((size_t)b * Tq + (tp - 1)) << 10) + c;
        float4 v0 = *(const float4*)(src);
        float4 v1 = *(const float4*)(src + 4);
        o[0]=(f16)v0.x; o[1]=(f16)v0.y; o[2]=(f16)v0.z; o[3]=(f16)v0.w;
        o[4]=(f16)v1.x; o[5]=(f16)v1.y; o[6]=(f16)v1.z; o[7]=(f16)v1.w;
    }
    *(f16x8*)(Xs + idx) = o;
}

// ---------------- prep: W^T f16 [N=3072][K=2048] ----------------
__global__ void prep_wt(const float* __restrict__ w, f16* __restrict__ WT) {
    __shared__ float t[32][33];
    int kb = blockIdx.x * 32, nb = blockIdx.y * 32;
    int tx = threadIdx.x & 31, ty = threadIdx.x >> 5;
#pragma unroll
    for (int j = 0; j < 32; j += 8)
        t[ty + j][tx] = w[(size_t)(kb + ty + j) * Nq + nb + tx];
    __syncthreads();
#pragma unroll
    for (int j = 0; j < 32; j += 8)
        WT[(size_t)(nb + ty + j) * Kq + kb + tx] = (f16)t[tx][ty + j];
}

// ---------------- 256x256 8-phase GEMM (32x32x16 MFMA) + gate epilogue ----------------
// 8 waves (2M x 4N): wave (wm,wn) owns rows {h*128 + wm*64 + 0..63 : h=0,1},
// cols {g*128 + wn*32 + 0..31 : g=0,1}. Phase (h,g) = 64x32 quadrant = 2 row-blocks
// of 32x32 x 4 K-steps = 8 MFMA. LDS [A0|B0|A1|B1] 32KB each, dbuf 128 KiB,
// st-swizzle: lds(row, cb) holds global(row, cb ^ ((row&7)<<4)).
__global__ __launch_bounds__(512, 2) void gemm_gates8(
    const f16* __restrict__ Xs, const f16* __restrict__ WT,
    const float* __restrict__ bias,
    f16* __restrict__ H, f16* __restrict__ F, f16* __restrict__ O)
{
    __shared__ __align__(16) f16 smem[65536];   // 128 KiB
    const int tid  = threadIdx.x;
    const int lane = tid & 63;
    const int wave = tid >> 6;
    const int wm = wave >> 2;            // 0..1
    const int wn = wave & 3;             // 0..3

    // T1: XCD swizzle, nwg=768 (768%8==0), chunk=96, N-minor for A-panel L2 reuse
    const int wg  = blockIdx.x;
    const int swz = (wg & 7) * 96 + (wg >> 3);
    const int mT  = swz / 12, nT = swz - mT * 12;
    const int rM  = mT * 256;
    const int nB  = nT * 256;
    const int b   = rM >> 11;
    const int t0  = rM & (Tq - 1);
    const size_t xsRow0 = (size_t)b * (Tq + 1) + t0;

    // staging: thread covers LDS bytes tid*16 (+8192), i.e. half-tile row (tid>>3)+64i
    const int srow = tid >> 3;
    const int scol = (((tid & 7) ^ (srow & 7))) * 8;   // pre-swizzled source col (f16)
    const f16* Abase = Xs + (xsRow0 + srow) * (size_t)Cq + scol;   // lda = Cq (overlapping windows)
    const f16* Bbase = WT + (size_t)(nB + srow) * Kq + scol;
    const int dstT = tid * 16;

#define STAGE_A(c, h, kt) do { \
    const f16* _s = Abase + (size_t)((h) * 128) * Cq + (kt) * 64; \
    int _d = (c) * 65536 + (h) * 16384 + dstT; \
    __builtin_amdgcn_global_load_lds((const AS1 void*)_s, \
        (AS3 void*)((char*)smem + _d), 16, 0, 0); \
    __builtin_amdgcn_global_load_lds((const AS1 void*)(_s + (size_t)64 * Cq), \
        (AS3 void*)((char*)smem + _d + 8192), 16, 0, 0); \
} while (0)

#define STAGE_B(c, h, kt) do { \
    const f16* _s = Bbase + (size_t)((h) * 128) * Kq + (kt) * 64; \
    int _d = 32768 + (c) * 65536 + (h) * 16384 + dstT; \
    __builtin_amdgcn_global_load_lds((const AS1 void*)_s, \
        (AS3 void*)((char*)smem + _d), 16, 0, 0); \
    __builtin_amdgcn_global_load_lds((const AS1 void*)(_s + (size_t)64 * Kq), \
        (AS3 void*)((char*)smem + _d + 8192), 16, 0, 0); \
} while (0)

    // ds_read per-lane constants (32x32x16 fragment layout):
    //   A frag (row-block rb, k-step ks): row = wm*64 + rb*32 + (lane&31),
    //     byte col = (ks*32 + (lane>>5)*16) ^ ((row&7)<<4); row&7 == lane&7
    //   B frag (col-block = wn, k-step ks): row = wn*32 + (lane&31), same col pattern
    const int rA0 = (wm * 64 + (lane & 31)) * 128;       // rb=0 row byte offset
    const int rB0 = (wn * 32 + (lane & 31)) * 128;
    const int csw = ((lane >> 5) * 16) ^ ((lane & 7) << 4);  // ks=0 swizzled byte col

    f32x16 acc[2][2][2] = {};    // [h][g][rb]
    f16x8 af[2][4], bg0[4], bg1[4];

#define LOADA(c, h) do { \
    const char* _a = (const char*)smem + (c) * 65536 + (h) * 16384; \
    _Pragma("unroll") \
    for (int rb = 0; rb < 2; rb++) \
    _Pragma("unroll") \
    for (int ks = 0; ks < 4; ks++) \
        af[rb][ks] = *(const f16x8*)(_a + rA0 + rb * 4096 + ((ks * 32) ^ csw)); \
} while (0)

#define LOADB(c, g, breg) do { \
    const char* _b = (const char*)smem + 32768 + (c) * 65536 + (g) * 16384; \
    _Pragma("unroll") \
    for (int ks = 0; ks < 4; ks++) \
        breg[ks] = *(const f16x8*)(_b + rB0 + ((ks * 32) ^ csw)); \
} while (0)

#define MM(h, g, breg) do { \
    _Pragma("unroll") \
    for (int rb = 0; rb < 2; rb++) \
    _Pragma("unroll") \
    for (int ks = 0; ks < 4; ks++) \
        acc[h][g][rb] = __builtin_amdgcn_mfma_f32_32x32x16_f16(af[rb][ks], breg[ks], acc[h][g][rb], 0, 0, 0); \
} while (0)

#define BAR() __builtin_amdgcn_s_barrier()
#define LGKM0() do { asm volatile("s_waitcnt lgkmcnt(0)" ::: "memory"); \
                     __builtin_amdgcn_sched_barrier(0); } while (0)
#define VM4() asm volatile("s_waitcnt vmcnt(4)" ::: "memory")

// One K-tile (BK=64) = 4 phases; stage next K-tile's half-tiles (Alo,Blo,Bhi,Ahi)
// one per phase into the other buffer. vmcnt(4) at ends of P1/P2/P4:
//   end-P1 drains Bhi(cur) [needed P2]; end-P2 drains Ahi(cur) [needed P3];
//   end-P4 drains Alo,Blo(next) [needed next P1].
#define KTILE(c, ktn) do { \
    /*P1*/ LOADA(c, 0); LOADB(c, 0, bg0); STAGE_A(1 - (c), 0, ktn); BAR(); LGKM0(); \
           __builtin_amdgcn_s_setprio(1); MM(0, 0, bg0); __builtin_amdgcn_s_setprio(0); VM4(); BAR(); \
    /*P2*/ LOADB(c, 1, bg1); STAGE_B(1 - (c), 0, ktn); BAR(); LGKM0(); \
           __builtin_amdgcn_s_setprio(1); MM(0, 1, bg1); __builtin_amdgcn_s_setprio(0); VM4(); BAR(); \
    /*P3*/ LOADA(c, 1); STAGE_B(1 - (c), 1, ktn); BAR(); LGKM0(); \
           __builtin_amdgcn_s_setprio(1); MM(1, 0, bg0); __builtin_amdgcn_s_setprio(0); BAR(); \
    /*P4*/ STAGE_A(1 - (c), 1, ktn); BAR(); LGKM0(); \
           __builtin_amdgcn_s_setprio(1); MM(1, 1, bg1); __builtin_amdgcn_s_setprio(0); VM4(); BAR(); \
} while (0)

    // prologue: K-tile 0 into buf0 in first-read order; vmcnt(4) -> Alo,Blo landed
    STAGE_A(0, 0, 0); STAGE_B(0, 0, 0); STAGE_B(0, 1, 0); STAGE_A(0, 1, 0);
    asm volatile("s_waitcnt vmcnt(4)" ::: "memory");
    BAR();

    for (int t = 0; t < 32; t += 2) {
        KTILE(0, t + 1);
        KTILE(1, t + 2);   // t+2==32 on last iter: garbage stage, in-bounds, never consumed
    }

    // epilogue: 32x32 C/D layout col=lane&31, row=(reg&3)+8*(reg>>2)+4*(lane>>5)
    const int gate = nB >> 10;                  // each 256-col tile lies in one gate
    f16* G = (gate == 0) ? H : ((gate == 1) ? F : O);
    const int rowb = ((lane >> 5) << 2);        // 4*(lane>>5)
#pragma unroll
    for (int h = 0; h < 2; h++)
#pragma unroll
    for (int g = 0; g < 2; g++) {
        const int col = nB + g * 128 + wn * 32 + (lane & 31);
        const int u = col & (Uq - 1);
        const float bv = bias[col];
#pragma unroll
        for (int rb = 0; rb < 2; rb++)
#pragma unroll
        for (int reg = 0; reg < 16; reg++) {
            const int row = rM + h * 128 + wm * 64 + rb * 32 + (reg & 3) + ((reg >> 2) << 3) + rowb;
            float v = acc[h][g][rb][reg] + bv;
            float r;
            if (gate == 0) r = 1.0f - 2.0f / (__expf(2.0f * v) + 1.0f);  // tanh
            else           r = 1.0f / (1.0f + __expf(-v));                // sigmoid
            G[(size_t)row * Uq + u] = (f16)r;
        }
    }
}

// ---------------- fo-pool scan (chunked, 3 passes) ----------------
__global__ void scan_pass1(const f16* __restrict__ F, const f16* __restrict__ H,
                           float* __restrict__ Ach, float* __restrict__ Bch) {
    int idx = blockIdx.x * blockDim.x + threadIdx.x;
    int u  = idx & (Uq - 1);
    int ch = (idx >> 10) & (NCH - 1);
    int b  = idx >> 15;
    size_t base = ((size_t)b * Tq + ch * CHL) * Uq + u;
    float a = 1.0f, c = 0.0f;
    for (int i = 0; i < CHL; i++) {
        float f = (float)F[base + (size_t)i * Uq];
        float h = (float)H[base + (size_t)i * Uq];
        c = f * c + (1.0f - f) * h;
        a *= f;
    }
    Ach[idx] = a;
    Bch[idx] = c;
}

__global__ void scan_pass2(const float* __restrict__ Ach, const float* __restrict__ Bch,
                           float* __restrict__ Cin) {
    int idx = blockIdx.x * blockDim.x + threadIdx.x;
    int u = idx & (Uq - 1);
    int b = idx >> 10;
    float c = 0.0f;
    for (int ch = 0; ch < NCH; ch++) {
        int o = ((b * NCH) + ch) * Uq + u;
        Cin[o] = c;
        c = Ach[o] * c + Bch[o];
    }
}

__global__ void scan_pass3(const f16* __restrict__ F, const f16* __restrict__ H,
                           const f16* __restrict__ O, const float* __restrict__ Cin,
                           float* __restrict__ out) {
    int idx = blockIdx.x * blockDim.x + threadIdx.x;
    int u  = idx & (Uq - 1);
    int ch = (idx >> 10) & (NCH - 1);
    int b  = idx >> 15;
    size_t base = ((size_t)b * Tq + ch * CHL) * Uq + u;
    float c = Cin[idx];
    for (int i = 0; i < CHL; i++) {
        float f = (float)F[base + (size_t)i * Uq];
        float h = (float)H[base + (size_t)i * Uq];
        c = f * c + (1.0f - f) * h;
        out[base + (size_t)i * Uq] = (float)O[base + (size_t)i * Uq] * c;
    }
}

// ---------------- launch ----------------
extern "C" void kernel_launch(void* const* d_in, const int* in_sizes, int n_in,
                              void* d_out, int out_size, void* d_ws, size_t ws_size,
                              hipStream_t stream) {
    const float* x    = (const float*)d_in[0];
    const float* w    = (const float*)d_in[1];
    const float* bias = (const float*)d_in[2];
    float* out = (float*)d_out;
    char* ws = (char*)d_ws;

    f16* Xs   = (f16*)(ws);                       // 8*2049*1024*2 = 33,570,816
    f16* WT   = (f16*)(ws + 33570816);            // 12,582,912
    f16* Hh   = (f16*)(ws + 46153728);            // 33,554,432
    f16* Fh   = (f16*)(ws + 79708160);            // 33,554,432
    f16* Oh   = (f16*)(ws + 113262592);           // 33,554,432
    float* Ach = (float*)(ws + 146817024);        // 1,048,576
    float* Bch = (float*)(ws + 147865600);        // 1,048,576
    float* Cin = (float*)(ws + 148914176);        // 1,048,576

    prep_xs<<<(Bq * (Tq + 1) * Cq) / (8 * 256), 256, 0, stream>>>(x, Xs);
    prep_wt<<<dim3(Kq / 32, Nq / 32), 256, 0, stream>>>(w, WT);
    gemm_gates8<<<(Mq / 256) * (Nq / 256), 512, 0, stream>>>(Xs, WT, bias, Hh, Fh, Oh);
    scan_pass1<<<(Bq * NCH * Uq) / 256, 256, 0, stream>>>(Fh, Hh, Ach, Bch);
    scan_pass2<<<(Bq * Uq) / 256, 256, 0, stream>>>(Ach, Bch, Cin);
    scan_pass3<<<(Bq * NCH * Uq) / 256, 256, 0, stream>>>(Fh, Hh, Oh, Cin, out);
}

// Round 5
// 256.569 us; speedup vs baseline: 1.1309x; 1.1309x over previous
//
#include <hip/hip_runtime.h>

// QRNN fused: causal conv1d(window=2) as f16 MFMA GEMM + gates + fo-pool scan.
// Shapes: B=8, T=2048, C=1024, U=1024 -> GEMM M=16384, K=2048, N=3072.
// R5: revert to 16x16x32 (R3, conflict-free swizzle); add in-wave register-load
//     pipelining: ds_reads lead their consuming phase by one, counted lgkmcnt(N),
//     barriers 8->3 per K-tile (only where staged half-tiles are first read).

typedef _Float16 f16;
typedef _Float16 f16x8 __attribute__((ext_vector_type(8)));
typedef float    f32x4 __attribute__((ext_vector_type(4)));

#define Bq 8
#define Tq 2048
#define Cq 1024
#define Uq 1024
#define Mq (Bq*Tq)    // 16384
#define Kq (2*Cq)     // 2048
#define Nq (3*Uq)     // 3072
#define NCH 32
#define CHL (Tq/NCH)

#define AS1 __attribute__((address_space(1)))
#define AS3 __attribute__((address_space(3)))

// ---------------- prep: Xs[b][1+t][c] = x[b][t][c] (f16), Xs[b][0][:] = 0 ----------------
__global__ void prep_xs(const float* __restrict__ x, f16* __restrict__ Xs) {
    long long idx = ((long long)blockIdx.x * blockDim.x + threadIdx.x) * 8;
    int c = (int)(idx & (Cq - 1));
    long long row = idx >> 10;
    int tp = (int)(row % (Tq + 1));
    int b  = (int)(row / (Tq + 1));
    f16x8 o;
    if (tp == 0) {
#pragma unroll
        for (int j = 0; j < 8; j++) o[j] = (f16)0.0f;
    } else {
        const float* src = x + (((size_t)b * Tq + (tp - 1)) << 10) + c;
        float4 v0 = *(const float4*)(src);
        float4 v1 = *(const float4*)(src + 4);
        o[0]=(f16)v0.x; o[1]=(f16)v0.y; o[2]=(f16)v0.z; o[3]=(f16)v0.w;
        o[4]=(f16)v1.x; o[5]=(f16)v1.y; o[6]=(f16)v1.z; o[7]=(f16)v1.w;
    }
    *(f16x8*)(Xs + idx) = o;
}

// ---------------- prep: W^T f16 [N=3072][K=2048] ----------------
__global__ void prep_wt(const float* __restrict__ w, f16* __restrict__ WT) {
    __shared__ float t[32][33];
    int kb = blockIdx.x * 32, nb = blockIdx.y * 32;
    int tx = threadIdx.x & 31, ty = threadIdx.x >> 5;
#pragma unroll
    for (int j = 0; j < 32; j += 8)
        t[ty + j][tx] = w[(size_t)(kb + ty + j) * Nq + nb + tx];
    __syncthreads();
#pragma unroll
    for (int j = 0; j < 32; j += 8)
        WT[(size_t)(nb + ty + j) * Kq + kb + tx] = (f16)t[tx][ty + j];
}

// ---------------- 256x256 pipelined 4-phase GEMM + gate epilogue ----------------
// 8 waves (2M x 4N): wave (wm,wn) owns rows {h*128 + wm*64 : h=0,1}(64 each),
// cols {g*128 + wn*32 : g=0,1}(32 each). Phase (h,g) = 16 MFMA 16x16x32.
// LDS [A0|B0|A1|B1] 32KB each, dbuf 128KiB, swizzle lds(row,cb)=global(row, cb^((row&7)<<4)).
// Pipeline: phase p issues ds_reads for phase p+1, waits lgkmcnt(#issued) so only
// phase p's own operands are drained -> MFMA overlaps next phase's LDS reads.
__global__ __launch_bounds__(512, 2) void gemm_gates8(
    const f16* __restrict__ Xs, const f16* __restrict__ WT,
    const float* __restrict__ bias,
    f16* __restrict__ H, f16* __restrict__ F, f16* __restrict__ O)
{
    __shared__ __align__(16) f16 smem[65536];   // 128 KiB
    const int tid  = threadIdx.x;
    const int lane = tid & 63;
    const int wave = tid >> 6;
    const int wm = wave >> 2;            // 0..1
    const int wn = wave & 3;             // 0..3

    // T1: XCD swizzle, nwg=768 (768%8==0), chunk=96, N-minor for A-panel L2 reuse
    const int wg  = blockIdx.x;
    const int swz = (wg & 7) * 96 + (wg >> 3);
    const int mT  = swz / 12, nT = swz - mT * 12;
    const int rM  = mT * 256;
    const int nB  = nT * 256;
    const int b   = rM >> 11;
    const int t0  = rM & (Tq - 1);
    const size_t xsRow0 = (size_t)b * (Tq + 1) + t0;

    // staging: thread covers LDS bytes tid*16 (+8192), i.e. half-tile row (tid>>3)+64i
    const int srow = tid >> 3;
    const int scol = (((tid & 7) ^ (srow & 7))) * 8;   // pre-swizzled source col (f16)
    const f16* Abase = Xs + (xsRow0 + srow) * (size_t)Cq + scol;   // lda = Cq (overlapping windows)
    const f16* Bbase = WT + (size_t)(nB + srow) * Kq + scol;
    const int dstT = tid * 16;

#define STAGE_A(c, h, kt) do { \
    const f16* _s = Abase + (size_t)((h) * 128) * Cq + (kt) * 64; \
    int _d = (c) * 65536 + (h) * 16384 + dstT; \
    __builtin_amdgcn_global_load_lds((const AS1 void*)_s, \
        (AS3 void*)((char*)smem + _d), 16, 0, 0); \
    __builtin_amdgcn_global_load_lds((const AS1 void*)(_s + (size_t)64 * Cq), \
        (AS3 void*)((char*)smem + _d + 8192), 16, 0, 0); \
} while (0)

#define STAGE_B(c, h, kt) do { \
    const f16* _s = Bbase + (size_t)((h) * 128) * Kq + (kt) * 64; \
    int _d = 32768 + (c) * 65536 + (h) * 16384 + dstT; \
    __builtin_amdgcn_global_load_lds((const AS1 void*)_s, \
        (AS3 void*)((char*)smem + _d), 16, 0, 0); \
    __builtin_amdgcn_global_load_lds((const AS1 void*)(_s + (size_t)64 * Kq), \
        (AS3 void*)((char*)smem + _d + 8192), 16, 0, 0); \
} while (0)

    // ds_read per-lane constants (16x16x32 fragment layout, as R3)
    const int rAoff = (wm * 64 + (lane & 15)) * 128;
    const int rBoff = (wn * 32 + (lane & 15)) * 128;
    const int ksw0 = (((lane >> 4) * 16)) ^ ((lane & 7) << 4);
    const int ksw1 = (64 + ((lane >> 4) * 16)) ^ ((lane & 7) << 4);

    f32x4 acc[2][2][4][2] = {};   // [h][g][mi][ni]
    f16x8 afA[4][2], afB[4][2], bg0[2][2], bg1[2][2];

#define LOADA_TO(c, h, dst) do { \
    const char* _a = (const char*)smem + (c) * 65536 + (h) * 16384 + rAoff; \
    _Pragma("unroll") \
    for (int mi = 0; mi < 4; mi++) { \
        dst[mi][0] = *(const f16x8*)(_a + mi * 2048 + ksw0); \
        dst[mi][1] = *(const f16x8*)(_a + mi * 2048 + ksw1); \
    } \
} while (0)

#define LOADB_TO(c, g, breg) do { \
    const char* _b = (const char*)smem + 32768 + (c) * 65536 + (g) * 16384 + rBoff; \
    _Pragma("unroll") \
    for (int ni = 0; ni < 2; ni++) { \
        breg[ni][0] = *(const f16x8*)(_b + ni * 2048 + ksw0); \
        breg[ni][1] = *(const f16x8*)(_b + ni * 2048 + ksw1); \
    } \
} while (0)

#define MM(h, g, afr, breg) do { \
    _Pragma("unroll") \
    for (int mi = 0; mi < 4; mi++) \
    _Pragma("unroll") \
    for (int ni = 0; ni < 2; ni++) { \
        acc[h][g][mi][ni] = __builtin_amdgcn_mfma_f32_16x16x32_f16(afr[mi][0], breg[ni][0], acc[h][g][mi][ni], 0, 0, 0); \
        acc[h][g][mi][ni] = __builtin_amdgcn_mfma_f32_16x16x32_f16(afr[mi][1], breg[ni][1], acc[h][g][mi][ni], 0, 0, 0); \
    } \
} while (0)

#define BAR()  __builtin_amdgcn_s_barrier()
#define SB0()  __builtin_amdgcn_sched_barrier(0)
#define PRIO1  __builtin_amdgcn_s_setprio(1)
#define PRIO0  __builtin_amdgcn_s_setprio(0)
#define LGKMC(n) asm volatile("s_waitcnt lgkmcnt(" #n ")" ::: "memory")
#define VM2()    asm volatile("s_waitcnt vmcnt(2)" ::: "memory")

// K-tile on buf c; stages tile ktn into buf c^1 (halves A0',B0',B1',A1' at P1..P4).
// Pre-read schedule (reads lead one phase):
//   P1: read B1(c)->bg1   | MM(0,0) afA,bg0 | end: VM2 (drains prev A1(c)) + BAR
//   P2: read A1(c)->afB   | MM(0,1) afA,bg1 | (no VM/BAR)
//   P3: (no reads)        | MM(1,0) afB,bg0 | end: VM2 (drains A0',B0') + BAR
//   P4: read A0,B0(c^1)->afA,bg0 | MM(1,1) afB,bg1 | end: VM2 (drains B1') + BAR
// lgkm count = #reads issued THIS phase -> waits exactly the previous phase's reads.
#define KTILE(c, ktn) do { \
    /*P1*/ LOADB_TO(c, 1, bg1); STAGE_A(1 - (c), 0, ktn); \
           SB0(); LGKMC(4); SB0(); \
           PRIO1; MM(0, 0, afA, bg0); PRIO0; \
           VM2(); BAR(); \
    /*P2*/ LOADA_TO(c, 1, afB); STAGE_B(1 - (c), 0, ktn); \
           SB0(); LGKMC(8); SB0(); \
           PRIO1; MM(0, 1, afA, bg1); PRIO0; \
    /*P3*/ STAGE_B(1 - (c), 1, ktn); \
           SB0(); LGKMC(0); SB0(); \
           PRIO1; MM(1, 0, afB, bg0); PRIO0; \
           VM2(); BAR(); \
    /*P4*/ LOADA_TO(1 - (c), 0, afA); LOADB_TO(1 - (c), 0, bg0); STAGE_A(1 - (c), 1, ktn); \
           SB0(); LGKMC(12); SB0(); \
           PRIO1; MM(1, 1, afB, bg1); PRIO0; \
           VM2(); BAR(); \
} while (0)

    // prologue: stage all 4 halves of K-tile 0 into buf0 (A0,B0,B1,A1 order);
    // vmcnt(2) leaves A1 in flight (drained by P1's end VM2 before P2 reads it).
    STAGE_A(0, 0, 0); STAGE_B(0, 0, 0); STAGE_B(0, 1, 0); STAGE_A(0, 1, 0);
    asm volatile("s_waitcnt vmcnt(2)" ::: "memory");
    BAR();
    LOADA_TO(0, 0, afA); LOADB_TO(0, 0, bg0);   // P1's LGKMC(4) drains these 12

    for (int t = 0; t < 32; t += 2) {
        KTILE(0, t + 1);
        KTILE(1, t + 2);   // t+2==32 on last iter: garbage stage/pre-read, never consumed
    }

    // epilogue: C/D layout col=lane&15, row=(lane>>4)*4+j
    const int gate = nB >> 10;
    f16* G = (gate == 0) ? H : ((gate == 1) ? F : O);
#pragma unroll
    for (int h = 0; h < 2; h++)
#pragma unroll
    for (int g = 0; g < 2; g++)
#pragma unroll
    for (int ni = 0; ni < 2; ni++) {
        const int col = nB + g * 128 + wn * 32 + ni * 16 + (lane & 15);
        const int u = col & (Uq - 1);
        const float bv = bias[col];
#pragma unroll
        for (int mi = 0; mi < 4; mi++)
#pragma unroll
        for (int j = 0; j < 4; j++) {
            const int row = rM + h * 128 + wm * 64 + mi * 16 + ((lane >> 4) << 2) + j;
            float v = acc[h][g][mi][ni][j] + bv;
            float r;
            if (gate == 0) r = 1.0f - 2.0f / (__expf(2.0f * v) + 1.0f);  // tanh
            else           r = 1.0f / (1.0f + __expf(-v));                // sigmoid
            G[(size_t)row * Uq + u] = (f16)r;
        }
    }
}

// ---------------- fo-pool scan (chunked, 3 passes) ----------------
__global__ void scan_pass1(const f16* __restrict__ F, const f16* __restrict__ H,
                           float* __restrict__ Ach, float* __restrict__ Bch) {
    int idx = blockIdx.x * blockDim.x + threadIdx.x;
    int u  = idx & (Uq - 1);
    int ch = (idx >> 10) & (NCH - 1);
    int b  = idx >> 15;
    size_t base = ((size_t)b * Tq + ch * CHL) * Uq + u;
    float a = 1.0f, c = 0.0f;
    for (int i = 0; i < CHL; i++) {
        float f = (float)F[base + (size_t)i * Uq];
        float h = (float)H[base + (size_t)i * Uq];
        c = f * c + (1.0f - f) * h;
        a *= f;
    }
    Ach[idx] = a;
    Bch[idx] = c;
}

__global__ void scan_pass2(const float* __restrict__ Ach, const float* __restrict__ Bch,
                           float* __restrict__ Cin) {
    int idx = blockIdx.x * blockDim.x + threadIdx.x;
    int u = idx & (Uq - 1);
    int b = idx >> 10;
    float c = 0.0f;
    for (int ch = 0; ch < NCH; ch++) {
        int o = ((b * NCH) + ch) * Uq + u;
        Cin[o] = c;
        c = Ach[o] * c + Bch[o];
    }
}

__global__ void scan_pass3(const f16* __restrict__ F, const f16* __restrict__ H,
                           const f16* __restrict__ O, const float* __restrict__ Cin,
                           float* __restrict__ out) {
    int idx = blockIdx.x * blockDim.x + threadIdx.x;
    int u  = idx & (Uq - 1);
    int ch = (idx >> 10) & (NCH - 1);
    int b  = idx >> 15;
    size_t base = ((size_t)b * Tq + ch * CHL) * Uq + u;
    float c = Cin[idx];
    for (int i = 0; i < CHL; i++) {
        float f = (float)F[base + (size_t)i * Uq];
        float h = (float)H[base + (size_t)i * Uq];
        c = f * c + (1.0f - f) * h;
        out[base + (size_t)i * Uq] = (float)O[base + (size_t)i * Uq] * c;
    }
}

// ---------------- launch ----------------
extern "C" void kernel_launch(void* const* d_in, const int* in_sizes, int n_in,
                              void* d_out, int out_size, void* d_ws, size_t ws_size,
                              hipStream_t stream) {
    const float* x    = (const float*)d_in[0];
    const float* w    = (const float*)d_in[1];
    const float* bias = (const float*)d_in[2];
    float* out = (float*)d_out;
    char* ws = (char*)d_ws;

    f16* Xs   = (f16*)(ws);                       // 8*2049*1024*2 = 33,570,816
    f16* WT   = (f16*)(ws + 33570816);            // 12,582,912
    f16* Hh   = (f16*)(ws + 46153728);            // 33,554,432
    f16* Fh   = (f16*)(ws + 79708160);            // 33,554,432
    f16* Oh   = (f16*)(ws + 113262592);           // 33,554,432
    float* Ach = (float*)(ws + 146817024);        // 1,048,576
    float* Bch = (float*)(ws + 147865600);        // 1,048,576
    float* Cin = (float*)(ws + 148914176);        // 1,048,576

    prep_xs<<<(Bq * (Tq + 1) * Cq) / (8 * 256), 256, 0, stream>>>(x, Xs);
    prep_wt<<<dim3(Kq / 32, Nq / 32), 256, 0, stream>>>(w, WT);
    gemm_gates8<<<(Mq / 256) * (Nq / 256), 512, 0, stream>>>(Xs, WT, bias, Hh, Fh, Oh);
    scan_pass1<<<(Bq * NCH * Uq) / 256, 256, 0, stream>>>(Fh, Hh, Ach, Bch);
    scan_pass2<<<(Bq * Uq) / 256, 256, 0, stream>>>(Ach, Bch, Cin);
    scan_pass3<<<(Bq * NCH * Uq) / 256, 256, 0, stream>>>(Fh, Hh, Oh, Cin, out);
}